// Round 1
// baseline (1104.821 us; speedup 1.0000x reference)
//
#include <hip/hip_runtime.h>

// Conv 7x7, 256 in-channels, 1 out-channel, valid, stride 1.
// x: (16,256,224,224) f32, w: (256,7,7) f32, bias: (1,) f32 -> out: (16,218,218) f32
//
// Strategy: 64Wx32H output tiles, 128 threads, 4x4 outputs/thread (keeps LDS
// traffic at 0.31 B/FLOP < b128 ceiling). 4-way channel split for occupancy,
// fp32 atomicAdd combine. Double-buffered LDS, reg-staged (issue-early loads).

#define C_IN 256
#define Hdim 224
#define Wdim 224
#define OHdim 218
#define OWdim 218
#define KS 7
#define NSPLIT 4
#define CPB 64          // channels per block
#define TILE_H 32
#define TILE_W 64
#define PATCH_H 38      // TILE_H + 6
#define PATCH_W 70      // TILE_W + 6
#define PW 72           // padded LDS row (16B-aligned rows, bank-spread)
#define NSLOT 18        // per patch row: 17 float4 + 1 float2
#define TOTSLOT (PATCH_H * NSLOT)   // 684
#define NTHREADS 128
#define NTH 7           // H tiles: 0,32,...,160,186
#define NTW 4           // W tiles: 0,64,128,154
#define TILES_PER_B (NTH * NTW)         // 28
#define BLOCKS_PER_B (TILES_PER_B * NSPLIT)  // 112
#define NBLOCKS (16 * BLOCKS_PER_B)     // 1792

__global__ __launch_bounds__(256) void init_out_kernel(float* __restrict__ out,
                                                       const float* __restrict__ bias,
                                                       int n) {
  int i = blockIdx.x * 256 + threadIdx.x;
  if (i < n) out[i] = bias[0];
}

__global__ __launch_bounds__(NTHREADS, 4) void conv7x7_kernel(
    const float* __restrict__ x, const float* __restrict__ w,
    float* __restrict__ out) {
  __shared__ float lds[2][PATCH_H][PW];

  const int tid = threadIdx.x;
  const int blk = blockIdx.x;
  const int cs   = blk & (NSPLIT - 1);
  const int t2   = blk >> 2;
  const int tile = t2 % TILES_PER_B;
  const int b    = t2 / TILES_PER_B;
  const int th   = tile >> 2;   // 0..6
  const int tw   = tile & 3;    // 0..3

  const int oh0 = (th == NTH - 1) ? (OHdim - TILE_H) : th * TILE_H;  // 186 at edge
  const int ow0 = (tw == NTW - 1) ? (OWdim - TILE_W) : tw * TILE_W;  // 154 at edge
  // owner ranges (disjoint partition of [0,218) so overlapped tiles don't double-add)
  const int rlo = (th == NTH - 1) ? (NTH - 1) * TILE_H : oh0;        // 192 at edge
  const int rhi = (th == NTH - 1) ? OHdim : oh0 + TILE_H;
  const int clo = (tw == NTW - 1) ? (NTW - 1) * TILE_W : ow0;        // 192 at edge
  const int chi = (tw == NTW - 1) ? OWdim : ow0 + TILE_W;

  const int tx = tid & 15;   // 16 col-groups of 4
  const int ty = tid >> 4;   // 8 row-groups of 4

  const int c0 = cs * CPB;
  const float* xbase = x + (size_t)(b * C_IN + c0) * (Hdim * Wdim)
                         + (size_t)oh0 * Wdim + ow0;

  float4 sv[6];  // staged global data for one channel (issue-early)

  auto stage_load = [&](int cc) {
    const float* xc = xbase + (size_t)cc * (Hdim * Wdim);
    #pragma unroll
    for (int k = 0; k < 6; ++k) {
      const int f = tid + k * NTHREADS;
      if (f < TOTSLOT) {
        const int row = f / NSLOT;
        const int cg  = f - row * NSLOT;
        const float* p = xc + row * Wdim;
        if (cg < 17) {
          sv[k] = *reinterpret_cast<const float4*>(p + cg * 4);
        } else {
          const float2 t = *reinterpret_cast<const float2*>(p + 68);
          sv[k].x = t.x; sv[k].y = t.y;
        }
      }
    }
  };

  auto stage_store = [&](int buf) {
    #pragma unroll
    for (int k = 0; k < 6; ++k) {
      const int f = tid + k * NTHREADS;
      if (f < TOTSLOT) {
        const int row = f / NSLOT;
        const int cg  = f - row * NSLOT;
        if (cg < 17) {
          *reinterpret_cast<float4*>(&lds[buf][row][cg * 4]) = sv[k];
        } else {
          *reinterpret_cast<float2*>(&lds[buf][row][68]) =
              make_float2(sv[k].x, sv[k].y);
        }
      }
    }
  };

  float acc[4][4];
  #pragma unroll
  for (int i = 0; i < 4; ++i) {
    #pragma unroll
    for (int j = 0; j < 4; ++j) acc[i][j] = 0.f;
  }

  stage_load(0);
  int buf = 0;
  for (int cc = 0; cc < CPB; ++cc) {
    stage_store(buf);                       // vmcnt wait lands here, after prev compute
    if (cc + 1 < CPB) stage_load(cc + 1);   // next channel's loads in flight over compute
    __syncthreads();                        // single barrier per channel (see pipeline note)

    const float* __restrict__ wp = w + (c0 + cc) * (KS * KS);  // uniform -> s_loads
    #pragma unroll
    for (int ir = 0; ir < 10; ++ir) {       // 10 input rows feed this thread's 4 out rows
      const float* pr = &lds[buf][ty * 4 + ir][tx * 4];
      const float4 a0 = *reinterpret_cast<const float4*>(pr);
      const float4 a1 = *reinterpret_cast<const float4*>(pr + 4);
      const float4 a2 = *reinterpret_cast<const float4*>(pr + 8);
      const float r[12] = {a0.x, a0.y, a0.z, a0.w,
                           a1.x, a1.y, a1.z, a1.w,
                           a2.x, a2.y, a2.z, a2.w};
      #pragma unroll
      for (int orow = 0; orow < 4; ++orow) {
        const int kh = ir - orow;
        if (kh >= 0 && kh < KS) {
          #pragma unroll
          for (int kw = 0; kw < KS; ++kw) {
            const float wv = wp[kh * KS + kw];
            #pragma unroll
            for (int j = 0; j < 4; ++j)
              acc[orow][j] = fmaf(r[kw + j], wv, acc[orow][j]);
          }
        }
      }
    }
    buf ^= 1;
  }

  const size_t ob = (size_t)b * (OHdim * OWdim);
  #pragma unroll
  for (int orow = 0; orow < 4; ++orow) {
    const int oh = oh0 + ty * 4 + orow;
    if (oh >= rlo && oh < rhi) {
      #pragma unroll
      for (int j = 0; j < 4; ++j) {
        const int ow_ = ow0 + tx * 4 + j;
        if (ow_ >= clo && ow_ < chi)
          atomicAdd(out + ob + (size_t)oh * OWdim + ow_, acc[orow][j]);
      }
    }
  }
}

extern "C" void kernel_launch(void* const* d_in, const int* in_sizes, int n_in,
                              void* d_out, int out_size, void* d_ws, size_t ws_size,
                              hipStream_t stream) {
  const float* x    = (const float*)d_in[0];
  const float* w    = (const float*)d_in[1];
  const float* bias = (const float*)d_in[2];
  float* out        = (float*)d_out;

  init_out_kernel<<<(out_size + 255) / 256, 256, 0, stream>>>(out, bias, out_size);
  conv7x7_kernel<<<NBLOCKS, NTHREADS, 0, stream>>>(x, w, out);
}

// Round 2
// 198.624 us; speedup vs baseline: 5.5624x; 5.5624x over previous
//
#include <hip/hip_runtime.h>

// Conv 7x7, 256 in-ch, 1 out-ch, valid -> (16,218,218), via bf16 MFMA + Toeplitz B.
// out[h0+m][w0+j] = sum_{c,kh,s} A[m][kk] * B[kk][j],  kk = kh*24 + s (pad to 192)
//   A[m][kk] = x_bf16[c][h0+m+kh][w0+s]   (LDS strip, 24 rows x 232 pitch, zero pads)
//   B[kk][j] = (0<=s-j<=6 && kh<7) ? w[c][kh][s-j] : 0   (precomputed in d_ws,
//              stored fragment-ordered so lane loads are one dwordx4)

#define C_IN 256
#define Hd 224
#define Wd 224
#define OHd 218
#define OWd 218
#define KS 7

#define NSPLIT 4
#define CPB (C_IN / NSPLIT)     // 64 channels per block
#define TH 16                   // output rows per block
#define NHB 14                  // h-bands (ceil 218/16)
#define NCHUNK 6                // K-chunks of 32 per channel (kh*24+s, 192 padded)
#define PITCH 232               // LDS row pitch (bf16 elems); 464B rows -> bank-stride 20
#define TROWS 24                // 22 staged rows + 2 zero pad rows
#define LDSE (TROWS * PITCH)    // ushorts per buffer
#define NTHREADS 128
#define NBLOCKS (16 * NHB * NSPLIT)   // 896

typedef short s16x8 __attribute__((ext_vector_type(8)));
typedef float f32x4 __attribute__((ext_vector_type(4)));

__device__ __forceinline__ unsigned short f2bf(float f) {
  unsigned int u = __float_as_uint(f);
  u = (u + 0x7FFFu + ((u >> 16) & 1u)) >> 16;   // RNE truncate to bf16
  return (unsigned short)u;
}

__global__ __launch_bounds__(256) void init_out_kernel(float* __restrict__ out,
                                                       const float* __restrict__ bias,
                                                       int n) {
  int i = blockIdx.x * 256 + threadIdx.x;
  if (i < n) out[i] = bias[0];
}

// Build Toeplitz B in fragment order: bws[((c*6+t)*64+l)*8+e] = B[kk(t,l,e)][j(l)]
__global__ __launch_bounds__(256) void build_b_kernel(const float* __restrict__ w,
                                                      unsigned short* __restrict__ bws) {
  int i = blockIdx.x * 256 + threadIdx.x;
  if (i >= C_IN * NCHUNK * 64) return;
  int l = i & 63;
  int t = (i >> 6) % NCHUNK;
  int c = i / (NCHUNK * 64);
  int q = l >> 4, j = l & 15;
  unsigned short v[8];
  #pragma unroll
  for (int e = 0; e < 8; ++e) {
    int kk = t * 32 + q * 8 + e;
    int kh = kk / 24, s = kk - kh * 24;
    int kw = s - j;
    float val = (kh < KS && kw >= 0 && kw < KS) ? w[(c * KS + kh) * KS + kw] : 0.f;
    v[e] = f2bf(val);
  }
  uint4 pk;
  pk.x = (unsigned)v[0] | ((unsigned)v[1] << 16);
  pk.y = (unsigned)v[2] | ((unsigned)v[3] << 16);
  pk.z = (unsigned)v[4] | ((unsigned)v[5] << 16);
  pk.w = (unsigned)v[6] | ((unsigned)v[7] << 16);
  *reinterpret_cast<uint4*>(bws + (size_t)i * 8) = pk;
}

__global__ __launch_bounds__(NTHREADS, 3) void conv_mfma_kernel(
    const float* __restrict__ x, const unsigned short* __restrict__ bws,
    float* __restrict__ out) {
  __shared__ unsigned short tile[2][LDSE];

  const int tid = threadIdx.x;
  const int bid = blockIdx.x;
  const int cs = bid & (NSPLIT - 1);
  const int t2 = bid >> 2;
  const int hb = t2 % NHB;
  const int b  = t2 / NHB;
  const int h0 = hb * TH;
  const int c0 = cs * CPB;

  // zero all of LDS once: pad rows/cols must stay finite-zero forever
  {
    uint4 z; z.x = z.y = z.z = z.w = 0u;
    for (int i = tid; i < 2 * LDSE / 8; i += NTHREADS)
      reinterpret_cast<uint4*>(&tile[0][0])[i] = z;
  }

  const int ln = tid & 63;
  const int wv = tid >> 6;   // wave id: j-blocks [wv*7, wv*7+7)
  const int q  = ln >> 4;
  const int m  = ln & 15;

  // per-chunk A byte offsets within a buffer: row (m+kh0), col s0 (kk0 = 32t+8q)
  int aoff[NCHUNK];
  #pragma unroll
  for (int t = 0; t < NCHUNK; ++t) {
    int k0 = t * 32 + q * 8;
    int kh0 = k0 / 24;
    int s0 = k0 - kh0 * 24;
    aoff[t] = (m + kh0) * (PITCH * 2) + s0 * 2;
  }

  // staging slots: 22 rows x 28 (16B bf16 groups) = 616 slots over 128 threads
  int goff[5]; int wboff[5]; bool sval[5];
  #pragma unroll
  for (int i = 0; i < 5; ++i) {
    int f = tid + NTHREADS * i;
    sval[i] = (f < 22 * 28);
    int r = sval[i] ? (f / 28) : 0;
    int cg = sval[i] ? (f - r * 28) : 0;
    int rg = h0 + r; if (rg > Hd - 1) rg = Hd - 1;   // clamp: garbage feeds only B=0/masked
    goff[i]  = rg * Wd + cg * 8;
    wboff[i] = r * (PITCH * 2) + cg * 16;
  }

  const float* xplane = x + (size_t)(b * C_IN + c0) * (Hd * Wd);

  float4 xa[5], xb[5];
  #pragma unroll
  for (int i = 0; i < 5; ++i) if (sval[i]) {
    xa[i] = *reinterpret_cast<const float4*>(xplane + goff[i]);
    xb[i] = *reinterpret_cast<const float4*>(xplane + goff[i] + 4);
  }

  f32x4 acc[7];
  #pragma unroll
  for (int jj = 0; jj < 7; ++jj) acc[jj] = (f32x4){0.f, 0.f, 0.f, 0.f};

  __syncthreads();   // zero-init visible before first ds_write

  int p = 0;
  for (int cc = 0; cc < CPB; ++cc) {
    // B fragments for this channel (coalesced 16B/lane, L2-resident 1.5MB)
    s16x8 bfr[NCHUNK];
    {
      const unsigned short* bp = bws + ((size_t)(c0 + cc) * NCHUNK * 64 + ln) * 8;
      #pragma unroll
      for (int t = 0; t < NCHUNK; ++t)
        bfr[t] = *reinterpret_cast<const s16x8*>(bp + t * 512);
    }
    // convert staged fp32 -> bf16, write LDS buf p
    #pragma unroll
    for (int i = 0; i < 5; ++i) if (sval[i]) {
      s16x8 v;
      v[0] = (short)f2bf(xa[i].x); v[1] = (short)f2bf(xa[i].y);
      v[2] = (short)f2bf(xa[i].z); v[3] = (short)f2bf(xa[i].w);
      v[4] = (short)f2bf(xb[i].x); v[5] = (short)f2bf(xb[i].y);
      v[6] = (short)f2bf(xb[i].z); v[7] = (short)f2bf(xb[i].w);
      *reinterpret_cast<s16x8*>(reinterpret_cast<char*>(&tile[p][0]) + wboff[i]) = v;
    }
    // issue next channel's global loads (latency hides under compute)
    if (cc + 1 < CPB) {
      const float* xn = xplane + (size_t)(cc + 1) * (Hd * Wd);
      #pragma unroll
      for (int i = 0; i < 5; ++i) if (sval[i]) {
        xa[i] = *reinterpret_cast<const float4*>(xn + goff[i]);
        xb[i] = *reinterpret_cast<const float4*>(xn + goff[i] + 4);
      }
    }
    __syncthreads();

    const char* base = reinterpret_cast<const char*>(&tile[p][0]);
    #pragma unroll
    for (int jj = 0; jj < 7; ++jj) {
      const int cb = (wv * 7 + jj) * 32;   // w0*2 bytes
      #pragma unroll
      for (int t = 0; t < NCHUNK; ++t) {
        s16x8 a = *reinterpret_cast<const s16x8*>(base + (aoff[t] + cb));
        acc[jj] = __builtin_amdgcn_mfma_f32_16x16x32_bf16(a, bfr[t], acc[jj], 0, 0, 0);
      }
    }
    p ^= 1;
  }

  // D layout: col = lane&15, row = (lane>>4)*4 + reg
  const size_t ob = (size_t)b * (OHd * OWd);
  const int oh_base = h0 + q * 4;
  #pragma unroll
  for (int jj = 0; jj < 7; ++jj) {
    const int ow = (wv * 7 + jj) * 16 + m;
    if (ow < OWd) {
      #pragma unroll
      for (int r = 0; r < 4; ++r) {
        const int oh = oh_base + r;
        if (oh < OHd)
          atomicAdd(out + ob + (size_t)oh * OWd + ow, acc[jj][r]);
      }
    }
  }
}

extern "C" void kernel_launch(void* const* d_in, const int* in_sizes, int n_in,
                              void* d_out, int out_size, void* d_ws, size_t ws_size,
                              hipStream_t stream) {
  const float* x    = (const float*)d_in[0];
  const float* w    = (const float*)d_in[1];
  const float* bias = (const float*)d_in[2];
  float* out        = (float*)d_out;
  unsigned short* bws = (unsigned short*)d_ws;   // needs 1.57 MB

  init_out_kernel<<<(out_size + 255) / 256, 256, 0, stream>>>(out, bias, out_size);
  build_b_kernel<<<(C_IN * NCHUNK * 64 + 255) / 256, 256, 0, stream>>>(w, bws);
  conv_mfma_kernel<<<NBLOCKS, NTHREADS, 0, stream>>>(x, bws, out);
}